// Round 1
// baseline (988.600 us; speedup 1.0000x reference)
//
#include <hip/hip_runtime.h>
#include <hip/hip_bf16.h>

#define NV 512
#define NB 128
#define NC 64

typedef float fv4 __attribute__((ext_vector_type(4)));
typedef float fv2 __attribute__((ext_vector_type(2)));
typedef float f32x4 __attribute__((ext_vector_type(4)));
typedef short bf8 __attribute__((ext_vector_type(8)));            // 8 bf16 = 4 VGPRs (MFMA A/B frag)
typedef unsigned short u16x4 __attribute__((ext_vector_type(4)));
typedef unsigned short u16x8 __attribute__((ext_vector_type(8)));

// f32 -> bf16 round-to-nearest-even
__device__ __forceinline__ unsigned short f2bf(float f) {
  unsigned u = __builtin_bit_cast(unsigned, f);
  u += 0x7fffu + ((u >> 16) & 1u);
  return (unsigned short)(u >> 16);
}

// LDS layouts (byte offsets), XOR-swizzled at 16B granularity so that
// stride-1KB column reads spread across banks (~2-way, free per m136).
// sB* : [64 cols][512 rows] bf16, 1KB per col-row
__device__ __forceinline__ int swzL(int c, int r) {
  return ((c << 10) + (r << 1)) ^ ((c & 7) << 4);
}
// sCh : [512 j][32 ii] bf16, 64B per j-row (2 swizzle bits available)
__device__ __forceinline__ int swzC(int j, int ii) {
  return ((j << 6) + (ii << 1)) ^ ((j & 3) << 4);
}

__global__ __launch_bounds__(256, 1)
void fused_cholTE_kernel(const float* __restrict__ covTE,
                         const float* __restrict__ chol,
                         float* __restrict__ out /* cholTE base */) {
  // 128KB static LDS: two 64KB operand buffers; 32KB staging aliases buf0.
  __shared__ __align__(16) char lds[131072];
  char* sB0 = lds;          // phase A/B: cholC [c][r];  phase C/D: phi [k][j]
  char* sB1 = lds + 65536;  // T1 [k][i]
  char* sCh = lds;          // phase C staging: cholT slab [j][ii] (aliases dead cholC)

  const int tid = threadIdx.x;
  const int w   = tid >> 6;      // wave 0..3
  const int lane = tid & 63;
  const int lr  = lane & 15;     // row/col within 16-tile
  const int lq  = lane >> 4;     // k-quarter 0..3

  const int wg = blockIdx.x;
  const int b  = wg & (NB - 1);         // batch; XCD = b%8 -> all 8 c-blocks of a batch share an XCD
  const int c0 = (wg >> 7) * NC;        // column block base

  const float* Cb = covTE + (size_t)b * NV * NV;
  const float* Lb = chol  + (size_t)b * NV * NV;
  float*       Ob = out   + (size_t)b * NV * NV;

  // ---------------- Phase A: cholC = chol[:, c0:c0+64] -> sB0 [c][r] bf16 ----------------
  {
    const int rr = tid >> 4;         // 0..15
    const int cc = (tid & 15) * 4;   // 0..60
    for (int p = 0; p < 32; ++p) {
      const int r = p * 16 + rr;
      fv4 v = *(const fv4*)(Lb + (size_t)r * NV + c0 + cc);
      *(unsigned short*)(sB0 + swzL(cc + 0, r)) = f2bf(v[0]);
      *(unsigned short*)(sB0 + swzL(cc + 1, r)) = f2bf(v[1]);
      *(unsigned short*)(sB0 + swzL(cc + 2, r)) = f2bf(v[2]);
      *(unsigned short*)(sB0 + swzL(cc + 3, r)) = f2bf(v[3]);
    }
  }
  __syncthreads();

  f32x4 acc[8][4];

  // ---------------- Phase B: T1 = covTE @ cholC  -> sB1 [k][i] bf16 ----------------
  #pragma unroll
  for (int m = 0; m < 8; ++m)
    #pragma unroll
    for (int n = 0; n < 4; ++n) acc[m][n] = (f32x4)0.f;

  for (int kb = 0; kb < 16; ++kb) {
    const int kbase = kb * 32 + lq * 8;     // this lane's 8 consecutive K (=chol row j)
    bf8 bfr[4];
    #pragma unroll
    for (int n = 0; n < 4; ++n)
      bfr[n] = *(const bf8*)(sB0 + swzL(n * 16 + lr, kbase));
    #pragma unroll
    for (int m = 0; m < 8; ++m) {
      const float* p = Cb + (size_t)(w * 128 + m * 16 + lr) * NV + kbase;
      fv4 a0 = *(const fv4*)p;
      fv4 a1 = *(const fv4*)(p + 4);
      u16x8 t;
      t[0]=f2bf(a0[0]); t[1]=f2bf(a0[1]); t[2]=f2bf(a0[2]); t[3]=f2bf(a0[3]);
      t[4]=f2bf(a1[0]); t[5]=f2bf(a1[1]); t[6]=f2bf(a1[2]); t[7]=f2bf(a1[3]);
      bf8 af = __builtin_bit_cast(bf8, t);
      #pragma unroll
      for (int n = 0; n < 4; ++n)
        acc[m][n] = __builtin_amdgcn_mfma_f32_16x16x32_bf16(af, bfr[n], acc[m][n], 0, 0, 0);
    }
  }
  // T1 (bf16) -> sB1; D-frag: row i = lq*4+q, col = lr
  #pragma unroll
  for (int m = 0; m < 8; ++m) {
    #pragma unroll
    for (int n = 0; n < 4; ++n) {
      f32x4 a = acc[m][n];
      u16x4 pk;
      pk[0]=f2bf(a[0]); pk[1]=f2bf(a[1]); pk[2]=f2bf(a[2]); pk[3]=f2bf(a[3]);
      *(u16x4*)(sB1 + swzL(n * 16 + lr, w * 128 + m * 16 + lq * 4)) = pk;
    }
  }
  __syncthreads();

  // ---------------- Phase C: phi = cholT @ T1 (masked) -> sB0 [k][j] bf16 ----------------
  #pragma unroll
  for (int m = 0; m < 8; ++m)
    #pragma unroll
    for (int n = 0; n < 4; ++n) acc[m][n] = (f32x4)0.f;

  for (int ib = 0; ib < 16; ++ib) {
    // stage chol[ib*32 .. +32][:] transposed: sCh[j][ii] = chol[ib*32+ii][j]
    {
      const float* src = Lb + (size_t)(ib * 32) * NV + tid * 2;  // j = 2*tid, 2*tid+1
      #pragma unroll
      for (int o = 0; o < 4; ++o) {
        u16x8 p0, p1;
        #pragma unroll
        for (int r = 0; r < 8; ++r) {
          fv2 v = *(const fv2*)(src + (size_t)(o * 8 + r) * NV);
          p0[r] = f2bf(v[0]);
          p1[r] = f2bf(v[1]);
        }
        *(u16x8*)(sCh + swzC(2 * tid + 0, o * 8)) = p0;
        *(u16x8*)(sCh + swzC(2 * tid + 1, o * 8)) = p1;
      }
    }
    __syncthreads();
    bf8 bt[4];
    #pragma unroll
    for (int n = 0; n < 4; ++n)
      bt[n] = *(const bf8*)(sB1 + swzL(n * 16 + lr, ib * 32 + lq * 8));
    #pragma unroll
    for (int jt = 0; jt < 8; ++jt) {
      bf8 af = *(const bf8*)(sCh + swzC(w * 128 + jt * 16 + lr, lq * 8));
      #pragma unroll
      for (int n = 0; n < 4; ++n)
        acc[jt][n] = __builtin_amdgcn_mfma_f32_16x16x32_bf16(af, bt[n], acc[jt][n], 0, 0, 0);
    }
    __syncthreads();
  }

  // mask (strict lower = 1, diag = 0.5, upper = 0) and write phi -> sB0 [k][j]
  #pragma unroll
  for (int jt = 0; jt < 8; ++jt) {
    #pragma unroll
    for (int n = 0; n < 4; ++n) {
      f32x4 a = acc[jt][n];
      const int gk = c0 + n * 16 + lr;          // global column of phi
      const int j0 = w * 128 + jt * 16 + lq * 4;
      u16x4 pk;
      #pragma unroll
      for (int q = 0; q < 4; ++q) {
        const int j = j0 + q;                   // global row of phi
        float f = (j > gk) ? a[q] : ((j == gk) ? 0.5f * a[q] : 0.f);
        pk[q] = f2bf(f);
      }
      *(u16x4*)(sB0 + swzL(n * 16 + lr, j0)) = pk;
    }
  }
  __syncthreads();

  // ---------------- Phase D: out = -chol @ phi ----------------
  #pragma unroll
  for (int m = 0; m < 8; ++m)
    #pragma unroll
    for (int n = 0; n < 4; ++n) acc[m][n] = (f32x4)0.f;

  for (int kb = 0; kb < 16; ++kb) {
    const int kbase = kb * 32 + lq * 8;         // K = phi row j
    bf8 bp[4];
    #pragma unroll
    for (int n = 0; n < 4; ++n)
      bp[n] = *(const bf8*)(sB0 + swzL(n * 16 + lr, kbase));
    #pragma unroll
    for (int m = 0; m < 8; ++m) {
      const float* p = Lb + (size_t)(w * 128 + m * 16 + lr) * NV + kbase;
      fv4 a0 = *(const fv4*)p;
      fv4 a1 = *(const fv4*)(p + 4);
      u16x8 t;
      t[0]=f2bf(a0[0]); t[1]=f2bf(a0[1]); t[2]=f2bf(a0[2]); t[3]=f2bf(a0[3]);
      t[4]=f2bf(a1[0]); t[5]=f2bf(a1[1]); t[6]=f2bf(a1[2]); t[7]=f2bf(a1[3]);
      bf8 af = __builtin_bit_cast(bf8, t);
      #pragma unroll
      for (int n = 0; n < 4; ++n)
        acc[m][n] = __builtin_amdgcn_mfma_f32_16x16x32_bf16(af, bp[n], acc[m][n], 0, 0, 0);
    }
  }
  // write output (negated)
  #pragma unroll
  for (int m = 0; m < 8; ++m) {
    const int i0 = w * 128 + m * 16 + lq * 4;
    #pragma unroll
    for (int n = 0; n < 4; ++n) {
      f32x4 a = acc[m][n];
      const int col = c0 + n * 16 + lr;
      #pragma unroll
      for (int q = 0; q < 4; ++q)
        Ob[(size_t)(i0 + q) * NV + col] = -a[q];
    }
  }
}

extern "C" void kernel_launch(void* const* d_in, const int* in_sizes, int n_in,
                              void* d_out, int out_size, void* d_ws, size_t ws_size,
                              hipStream_t stream) {
  const float* muTE  = (const float*)d_in[0];
  const float* covTE = (const float*)d_in[1];
  const float* chol  = (const float*)d_in[2];
  float* out = (float*)d_out;

  // Output 0: muTE passthrough (65536 f32)
  hipMemcpyAsync(out, muTE, (size_t)NB * NV * sizeof(float),
                 hipMemcpyDeviceToDevice, stream);

  // Output 1: cholTE [128,512,512] f32
  fused_cholTE_kernel<<<dim3(NB * (NV / NC)), dim3(256), 0, stream>>>(
      covTE, chol, out + (size_t)NB * NV);
}

// Round 2
// 388.682 us; speedup vs baseline: 2.5435x; 2.5435x over previous
//
#include <hip/hip_runtime.h>
#include <hip/hip_bf16.h>

#define NV 512
#define NB 128
#define NC 64

typedef float fv4 __attribute__((ext_vector_type(4)));
typedef float fv2 __attribute__((ext_vector_type(2)));
typedef float f32x4 __attribute__((ext_vector_type(4)));
typedef short bf8 __attribute__((ext_vector_type(8)));            // 8 bf16 = 4 VGPRs (MFMA A/B frag)
typedef unsigned short u16x4 __attribute__((ext_vector_type(4)));
typedef unsigned short u16x8 __attribute__((ext_vector_type(8)));

// f32 -> bf16 round-to-nearest-even
__device__ __forceinline__ unsigned short f2bf(float f) {
  unsigned u = __builtin_bit_cast(unsigned, f);
  u += 0x7fffu + ((u >> 16) & 1u);
  return (unsigned short)(u >> 16);
}

// sB* : [64 cols][512 rows] bf16, 1KB per col; XOR swizzle on 16B granules
__device__ __forceinline__ int swzL(int c, int r) {
  return ((c << 10) + (r << 1)) ^ ((c & 7) << 4);
}
// sCh : [512 j][32 ii] bf16, 64B per j-row
__device__ __forceinline__ int swzC(int j, int ii) {
  return ((j << 6) + (ii << 1)) ^ ((j & 3) << 4);
}

__global__ __launch_bounds__(1024, 1)
void fused_cholTE_kernel(const float* __restrict__ covTE,
                         const float* __restrict__ chol,
                         float* __restrict__ out /* cholTE base */) {
  // 128KB static LDS: two 64KB operand buffers; 32KB staging aliases buf0.
  __shared__ __align__(16) char lds[131072];
  char* sB0 = lds;          // phase A/B: cholC [c][r];  phase C/D: phi [c][j]
  char* sB1 = lds + 65536;  // T1 [c][i]
  char* sCh = lds;          // phase C staging: cholT slab [j][ii] (aliases dead cholC)

  const int tid  = threadIdx.x;
  const int w    = tid >> 6;     // wave 0..15
  const int lane = tid & 63;
  const int lr   = lane & 15;    // row/col within 16-tile
  const int lq   = lane >> 4;    // k-quarter 0..3

  // XCD-aware mapping: XCD = bid%8 gets batches [16*xcd, 16*xcd+16) with all
  // 8 c-blocks of a batch adjacent in dispatch order -> co-resident on one XCD.
  const int bid = blockIdx.x;
  const int xcd = bid & 7;
  const int s   = bid >> 3;            // 0..127 per XCD, in dispatch order
  const int b   = xcd * 16 + (s >> 3); // batch
  const int c0  = (s & 7) * NC;        // column block base

  const float* Cb = covTE + (size_t)b * NV * NV;
  const float* Lb = chol  + (size_t)b * NV * NV;
  float*       Ob = out   + (size_t)b * NV * NV;

  // ---------------- Phase A: cholC = chol[:, c0:c0+64] -> sB0 [c][r] bf16 ----------------
  {
    const int rr = tid >> 4;         // 0..63
    const int cc = (tid & 15) * 4;   // 0..60
    #pragma unroll
    for (int p = 0; p < 8; ++p) {
      const int r = p * 64 + rr;
      fv4 v = *(const fv4*)(Lb + (size_t)r * NV + c0 + cc);
      *(unsigned short*)(sB0 + swzL(cc + 0, r)) = f2bf(v[0]);
      *(unsigned short*)(sB0 + swzL(cc + 1, r)) = f2bf(v[1]);
      *(unsigned short*)(sB0 + swzL(cc + 2, r)) = f2bf(v[2]);
      *(unsigned short*)(sB0 + swzL(cc + 3, r)) = f2bf(v[3]);
    }
  }
  __syncthreads();

  f32x4 acc[2][4];

  // ---------------- Phase B: T1 = covTE @ cholC  -> sB1 [c][i] bf16 ----------------
  #pragma unroll
  for (int m = 0; m < 2; ++m)
    #pragma unroll
    for (int n = 0; n < 4; ++n) acc[m][n] = (f32x4)0.f;

  for (int kb = 0; kb < 16; ++kb) {
    const int kbase = kb * 32 + lq * 8;     // this lane's 8 consecutive K
    bf8 bfr[4];
    #pragma unroll
    for (int n = 0; n < 4; ++n)
      bfr[n] = *(const bf8*)(sB0 + swzL(n * 16 + lr, kbase));
    #pragma unroll
    for (int m = 0; m < 2; ++m) {
      const float* p = Cb + (size_t)(w * 32 + m * 16 + lr) * NV + kbase;
      fv4 a0 = *(const fv4*)p;
      fv4 a1 = *(const fv4*)(p + 4);
      u16x8 t;
      t[0]=f2bf(a0[0]); t[1]=f2bf(a0[1]); t[2]=f2bf(a0[2]); t[3]=f2bf(a0[3]);
      t[4]=f2bf(a1[0]); t[5]=f2bf(a1[1]); t[6]=f2bf(a1[2]); t[7]=f2bf(a1[3]);
      bf8 af = __builtin_bit_cast(bf8, t);
      #pragma unroll
      for (int n = 0; n < 4; ++n)
        acc[m][n] = __builtin_amdgcn_mfma_f32_16x16x32_bf16(af, bfr[n], acc[m][n], 0, 0, 0);
    }
  }
  // T1 (bf16) -> sB1; D-frag: row i = lq*4+q, col = lr
  #pragma unroll
  for (int m = 0; m < 2; ++m) {
    #pragma unroll
    for (int n = 0; n < 4; ++n) {
      f32x4 a = acc[m][n];
      u16x4 pk;
      pk[0]=f2bf(a[0]); pk[1]=f2bf(a[1]); pk[2]=f2bf(a[2]); pk[3]=f2bf(a[3]);
      *(u16x4*)(sB1 + swzL(n * 16 + lr, w * 32 + m * 16 + lq * 4)) = pk;
    }
  }
  __syncthreads();

  // ---------------- Phase C: phi = cholT @ T1 (masked) -> sB0 [c][j] bf16 ----------------
  #pragma unroll
  for (int m = 0; m < 2; ++m)
    #pragma unroll
    for (int n = 0; n < 4; ++n) acc[m][n] = (f32x4)0.f;

  // staging assignment: thread covers columns (sj, sj+1), rows so*8..so*8+7
  const int sj = (tid & 255) * 2;
  const int so = tid >> 8;            // 0..3

  fv2 raw[8];                         // raw f32 pairs for NEXT slab (T14 split)
  // prologue: stage slab 0
  {
    const float* src = Lb + (size_t)(so * 8) * NV + sj;
    #pragma unroll
    for (int r = 0; r < 8; ++r) raw[r] = *(const fv2*)(src + (size_t)r * NV);
    u16x8 p0, p1;
    #pragma unroll
    for (int r = 0; r < 8; ++r) { p0[r] = f2bf(raw[r][0]); p1[r] = f2bf(raw[r][1]); }
    *(u16x8*)(sCh + swzC(sj + 0, so * 8)) = p0;
    *(u16x8*)(sCh + swzC(sj + 1, so * 8)) = p1;
  }
  __syncthreads();

  for (int ib = 0; ib < 16; ++ib) {
    // issue next slab's global loads early (hide latency under MFMA below)
    if (ib + 1 < 16) {
      const float* src = Lb + (size_t)((ib + 1) * 32 + so * 8) * NV + sj;
      #pragma unroll
      for (int r = 0; r < 8; ++r) raw[r] = *(const fv2*)(src + (size_t)r * NV);
    }
    // compute on current slab
    bf8 bt[4];
    #pragma unroll
    for (int n = 0; n < 4; ++n)
      bt[n] = *(const bf8*)(sB1 + swzL(n * 16 + lr, ib * 32 + lq * 8));
    #pragma unroll
    for (int jt = 0; jt < 2; ++jt) {
      bf8 af = *(const bf8*)(sCh + swzC(w * 32 + jt * 16 + lr, lq * 8));
      #pragma unroll
      for (int n = 0; n < 4; ++n)
        acc[jt][n] = __builtin_amdgcn_mfma_f32_16x16x32_bf16(af, bt[n], acc[jt][n], 0, 0, 0);
    }
    __syncthreads();                  // all waves done reading sCh
    if (ib + 1 < 16) {
      u16x8 p0, p1;
      #pragma unroll
      for (int r = 0; r < 8; ++r) { p0[r] = f2bf(raw[r][0]); p1[r] = f2bf(raw[r][1]); }
      *(u16x8*)(sCh + swzC(sj + 0, so * 8)) = p0;
      *(u16x8*)(sCh + swzC(sj + 1, so * 8)) = p1;
    }
    __syncthreads();                  // sCh ready for next iter (or phi write)
  }

  // mask (strict lower = 1, diag = 0.5, upper = 0) and write phi -> sB0 [c][j]
  #pragma unroll
  for (int jt = 0; jt < 2; ++jt) {
    #pragma unroll
    for (int n = 0; n < 4; ++n) {
      f32x4 a = acc[jt][n];
      const int gk = c0 + n * 16 + lr;          // global column of phi
      const int j0 = w * 32 + jt * 16 + lq * 4;
      u16x4 pk;
      #pragma unroll
      for (int q = 0; q < 4; ++q) {
        const int j = j0 + q;                   // global row of phi
        float f = (j > gk) ? a[q] : ((j == gk) ? 0.5f * a[q] : 0.f);
        pk[q] = f2bf(f);
      }
      *(u16x4*)(sB0 + swzL(n * 16 + lr, j0)) = pk;
    }
  }
  __syncthreads();

  // ---------------- Phase D: out = -chol @ phi ----------------
  #pragma unroll
  for (int m = 0; m < 2; ++m)
    #pragma unroll
    for (int n = 0; n < 4; ++n) acc[m][n] = (f32x4)0.f;

  for (int kb = 0; kb < 16; ++kb) {
    const int kbase = kb * 32 + lq * 8;         // K = phi row j
    bf8 bp[4];
    #pragma unroll
    for (int n = 0; n < 4; ++n)
      bp[n] = *(const bf8*)(sB0 + swzL(n * 16 + lr, kbase));
    #pragma unroll
    for (int m = 0; m < 2; ++m) {
      const float* p = Lb + (size_t)(w * 32 + m * 16 + lr) * NV + kbase;
      fv4 a0 = *(const fv4*)p;
      fv4 a1 = *(const fv4*)(p + 4);
      u16x8 t;
      t[0]=f2bf(a0[0]); t[1]=f2bf(a0[1]); t[2]=f2bf(a0[2]); t[3]=f2bf(a0[3]);
      t[4]=f2bf(a1[0]); t[5]=f2bf(a1[1]); t[6]=f2bf(a1[2]); t[7]=f2bf(a1[3]);
      bf8 af = __builtin_bit_cast(bf8, t);
      #pragma unroll
      for (int n = 0; n < 4; ++n)
        acc[m][n] = __builtin_amdgcn_mfma_f32_16x16x32_bf16(af, bp[n], acc[m][n], 0, 0, 0);
    }
  }
  // write output (negated)
  #pragma unroll
  for (int m = 0; m < 2; ++m) {
    const int i0 = w * 32 + m * 16 + lq * 4;
    #pragma unroll
    for (int n = 0; n < 4; ++n) {
      f32x4 a = acc[m][n];
      const int col = c0 + n * 16 + lr;
      #pragma unroll
      for (int q = 0; q < 4; ++q)
        Ob[(size_t)(i0 + q) * NV + col] = -a[q];
    }
  }
}

extern "C" void kernel_launch(void* const* d_in, const int* in_sizes, int n_in,
                              void* d_out, int out_size, void* d_ws, size_t ws_size,
                              hipStream_t stream) {
  const float* muTE  = (const float*)d_in[0];
  const float* covTE = (const float*)d_in[1];
  const float* chol  = (const float*)d_in[2];
  float* out = (float*)d_out;

  // Output 0: muTE passthrough (65536 f32)
  hipMemcpyAsync(out, muTE, (size_t)NB * NV * sizeof(float),
                 hipMemcpyDeviceToDevice, stream);

  // Output 1: cholTE [128,512,512] f32
  fused_cholTE_kernel<<<dim3(NB * (NV / NC)), dim3(1024), 0, stream>>>(
      covTE, chol, out + (size_t)NB * NV);
}

// Round 3
// 368.771 us; speedup vs baseline: 2.6808x; 1.0540x over previous
//
#include <hip/hip_runtime.h>
#include <hip/hip_bf16.h>

#define NV 512
#define NB 128
#define NC 64

typedef float fv4 __attribute__((ext_vector_type(4)));
typedef float fv2 __attribute__((ext_vector_type(2)));
typedef float f32x4 __attribute__((ext_vector_type(4)));
typedef short bf8 __attribute__((ext_vector_type(8)));            // 8 bf16 = 4 VGPRs (MFMA A/B frag)
typedef unsigned short u16x4 __attribute__((ext_vector_type(4)));
typedef unsigned short u16x8 __attribute__((ext_vector_type(8)));

// f32 -> bf16 round-to-nearest-even
__device__ __forceinline__ unsigned short f2bf(float f) {
  unsigned u = __builtin_bit_cast(unsigned, f);
  u += 0x7fffu + ((u >> 16) & 1u);
  return (unsigned short)(u >> 16);
}

// sB* : [64 cols][512 rows] bf16, 1KB per col; XOR swizzle on 16B granules
__device__ __forceinline__ int swzL(int c, int r) {
  return ((c << 10) + (r << 1)) ^ ((c & 7) << 4);
}
// sCh : [512 j][32 ii] bf16, 64B per j-row (fallback kernel only)
__device__ __forceinline__ int swzC(int j, int ii) {
  return ((j << 6) + (ii << 1)) ^ ((j & 3) << 4);
}

__device__ __forceinline__ void gload_lds16(const void* g, void* l) {
  __builtin_amdgcn_global_load_lds(
      (const __attribute__((address_space(1))) unsigned int*)g,
      (__attribute__((address_space(3))) unsigned int*)l, 16, 0, 0);
}

// ---------------------------------------------------------------------------
// Kernel 1: LT[b][j][i] = bf16(chol[b][i][j])   (64 MB bf16 workspace)
// ---------------------------------------------------------------------------
__global__ __launch_bounds__(256, 4)
void convert_LT_kernel(const float* __restrict__ chol, unsigned short* __restrict__ LT) {
  __shared__ unsigned short T[64][72];   // T[c][r], pad 72 to spread banks
  const int bid = blockIdx.x;
  const int b  = bid >> 6;
  const int t  = bid & 63;
  const int ti = t >> 3, tj = t & 7;     // row-tile, col-tile of chol

  const float* src = chol + ((size_t)b * NV + ti * 64) * NV + tj * 64;
  {
    const int r0 = threadIdx.x >> 4;       // 0..15
    const int c4 = (threadIdx.x & 15) * 4; // 0..60
    #pragma unroll
    for (int p = 0; p < 4; ++p) {
      const int r = p * 16 + r0;
      fv4 v = *(const fv4*)(src + (size_t)r * NV + c4);
      T[c4 + 0][r] = f2bf(v[0]);
      T[c4 + 1][r] = f2bf(v[1]);
      T[c4 + 2][r] = f2bf(v[2]);
      T[c4 + 3][r] = f2bf(v[3]);
    }
  }
  __syncthreads();
  // write LT rows tj*64+c, cols ti*64..+64
  unsigned short* dst = LT + ((size_t)b * NV + tj * 64) * NV + ti * 64;
  const int c  = threadIdx.x >> 2;        // 0..63
  const int k8 = (threadIdx.x & 3) * 16;  // 0,16,32,48
  u16x8 o0, o1;
  #pragma unroll
  for (int q = 0; q < 8; ++q) { o0[q] = T[c][k8 + q]; o1[q] = T[c][k8 + 8 + q]; }
  *(u16x8*)(dst + (size_t)c * NV + k8)     = o0;
  *(u16x8*)(dst + (size_t)c * NV + k8 + 8) = o1;
}

// ---------------------------------------------------------------------------
// Kernel 2 (fast path): fused 3-GEMM chain, LT available in bf16
// ---------------------------------------------------------------------------
__global__ __launch_bounds__(1024, 1)
void fused_cholTE_fast(const float* __restrict__ covTE,
                       const float* __restrict__ chol,
                       const unsigned short* __restrict__ LT,
                       float* __restrict__ out) {
  __shared__ __align__(16) char lds[131072];
  char* sB0 = lds;          // phase A/B: cholC [c][r];  phase C/D: phi [c][j]
  char* sB1 = lds + 65536;  // T1 [c][i]

  const int tid  = threadIdx.x;
  const int w    = tid >> 6;     // wave 0..15
  const int lane = tid & 63;
  const int lr   = lane & 15;
  const int lq   = lane >> 4;

  const int bid = blockIdx.x;
  const int xcd = bid & 7;
  const int s   = bid >> 3;
  const int b   = xcd * 16 + (s >> 3);
  const int c0  = (s & 7) * NC;

  const float*          Cb  = covTE + (size_t)b * NV * NV;
  const float*          Lb  = chol  + (size_t)b * NV * NV;
  const unsigned short* LTb = LT    + (size_t)b * NV * NV;
  float*                Ob  = out   + (size_t)b * NV * NV;

  // -------- Phase A: stage chol columns c0..c0+63 = LT rows -> sB0 via global_load_lds
  // wave w stages cols {w, w+16, w+32, w+48}; 64 lanes x 16B = one 1KB column.
  // Swizzle applied on SOURCE granule (rule #21): LDS stays linear per column.
  #pragma unroll
  for (int cc = 0; cc < 4; ++cc) {
    const int c = cc * 16 + w;
    const unsigned short* src = LTb + (size_t)(c0 + c) * NV + ((lane ^ (c & 7)) * 8);
    gload_lds16(src, sB0 + c * 1024);
  }
  __syncthreads();

  f32x4 acc[2][4];

  // -------- Phase B: T1 = covTE @ cholC -> sB1 [c][i] bf16
  #pragma unroll
  for (int m = 0; m < 2; ++m)
    #pragma unroll
    for (int n = 0; n < 4; ++n) acc[m][n] = (f32x4)0.f;

  for (int kb = 0; kb < 16; ++kb) {
    const int kbase = kb * 32 + lq * 8;
    bf8 bfr[4];
    #pragma unroll
    for (int n = 0; n < 4; ++n)
      bfr[n] = *(const bf8*)(sB0 + swzL(n * 16 + lr, kbase));
    #pragma unroll
    for (int m = 0; m < 2; ++m) {
      const float* p = Cb + (size_t)(w * 32 + m * 16 + lr) * NV + kbase;
      fv4 a0 = *(const fv4*)p;
      fv4 a1 = *(const fv4*)(p + 4);
      u16x8 t;
      t[0]=f2bf(a0[0]); t[1]=f2bf(a0[1]); t[2]=f2bf(a0[2]); t[3]=f2bf(a0[3]);
      t[4]=f2bf(a1[0]); t[5]=f2bf(a1[1]); t[6]=f2bf(a1[2]); t[7]=f2bf(a1[3]);
      bf8 af = __builtin_bit_cast(bf8, t);
      #pragma unroll
      for (int n = 0; n < 4; ++n)
        acc[m][n] = __builtin_amdgcn_mfma_f32_16x16x32_bf16(af, bfr[n], acc[m][n], 0, 0, 0);
    }
  }
  #pragma unroll
  for (int m = 0; m < 2; ++m) {
    #pragma unroll
    for (int n = 0; n < 4; ++n) {
      f32x4 a = acc[m][n];
      u16x4 pk;
      pk[0]=f2bf(a[0]); pk[1]=f2bf(a[1]); pk[2]=f2bf(a[2]); pk[3]=f2bf(a[3]);
      *(u16x4*)(sB1 + swzL(n * 16 + lr, w * 32 + m * 16 + lq * 4)) = pk;
    }
  }
  __syncthreads();

  // -------- Phase C: phi = cholT @ T1 (masked) -> sB0 [c][j] bf16
  // A-operand = LT rows (K-contiguous bf16 in global) -> direct bf8 loads, no staging.
  #pragma unroll
  for (int m = 0; m < 2; ++m)
    #pragma unroll
    for (int n = 0; n < 4; ++n) acc[m][n] = (f32x4)0.f;

  for (int ib = 0; ib < 16; ++ib) {
    const int kbase = ib * 32 + lq * 8;      // reduction index i
    bf8 bt[4];
    #pragma unroll
    for (int n = 0; n < 4; ++n)
      bt[n] = *(const bf8*)(sB1 + swzL(n * 16 + lr, kbase));
    #pragma unroll
    for (int jt = 0; jt < 2; ++jt) {
      bf8 af = *(const bf8*)(LTb + (size_t)(w * 32 + jt * 16 + lr) * NV + kbase);
      #pragma unroll
      for (int n = 0; n < 4; ++n)
        acc[jt][n] = __builtin_amdgcn_mfma_f32_16x16x32_bf16(af, bt[n], acc[jt][n], 0, 0, 0);
    }
  }
  // mask (strict lower = 1, diag = 0.5, upper = 0), write phi -> sB0 [c][j]
  #pragma unroll
  for (int jt = 0; jt < 2; ++jt) {
    #pragma unroll
    for (int n = 0; n < 4; ++n) {
      f32x4 a = acc[jt][n];
      const int gk = c0 + n * 16 + lr;
      const int j0 = w * 32 + jt * 16 + lq * 4;
      u16x4 pk;
      #pragma unroll
      for (int q = 0; q < 4; ++q) {
        const int j = j0 + q;
        float f = (j > gk) ? a[q] : ((j == gk) ? 0.5f * a[q] : 0.f);
        pk[q] = f2bf(f);
      }
      *(u16x4*)(sB0 + swzL(n * 16 + lr, j0)) = pk;
    }
  }
  __syncthreads();

  // -------- Phase D: out = -chol @ phi
  #pragma unroll
  for (int m = 0; m < 2; ++m)
    #pragma unroll
    for (int n = 0; n < 4; ++n) acc[m][n] = (f32x4)0.f;

  for (int kb = 0; kb < 16; ++kb) {
    const int kbase = kb * 32 + lq * 8;
    bf8 bp[4];
    #pragma unroll
    for (int n = 0; n < 4; ++n)
      bp[n] = *(const bf8*)(sB0 + swzL(n * 16 + lr, kbase));
    #pragma unroll
    for (int m = 0; m < 2; ++m) {
      const float* p = Lb + (size_t)(w * 32 + m * 16 + lr) * NV + kbase;
      fv4 a0 = *(const fv4*)p;
      fv4 a1 = *(const fv4*)(p + 4);
      u16x8 t;
      t[0]=f2bf(a0[0]); t[1]=f2bf(a0[1]); t[2]=f2bf(a0[2]); t[3]=f2bf(a0[3]);
      t[4]=f2bf(a1[0]); t[5]=f2bf(a1[1]); t[6]=f2bf(a1[2]); t[7]=f2bf(a1[3]);
      bf8 af = __builtin_bit_cast(bf8, t);
      #pragma unroll
      for (int n = 0; n < 4; ++n)
        acc[m][n] = __builtin_amdgcn_mfma_f32_16x16x32_bf16(af, bp[n], acc[m][n], 0, 0, 0);
    }
  }
  #pragma unroll
  for (int m = 0; m < 2; ++m) {
    const int i0 = w * 32 + m * 16 + lq * 4;
    #pragma unroll
    for (int n = 0; n < 4; ++n) {
      f32x4 a = acc[m][n];
      const int col = c0 + n * 16 + lr;
      #pragma unroll
      for (int q = 0; q < 4; ++q)
        Ob[(size_t)(i0 + q) * NV + col] = -a[q];
    }
  }
}

// ---------------------------------------------------------------------------
// Fallback (R1 kernel, passing at 389us) for ws_size < 64 MB
// ---------------------------------------------------------------------------
__global__ __launch_bounds__(1024, 1)
void fused_cholTE_fallback(const float* __restrict__ covTE,
                           const float* __restrict__ chol,
                           float* __restrict__ out) {
  __shared__ __align__(16) char lds[131072];
  char* sB0 = lds;
  char* sB1 = lds + 65536;
  char* sCh = lds;

  const int tid  = threadIdx.x;
  const int w    = tid >> 6;
  const int lane = tid & 63;
  const int lr   = lane & 15;
  const int lq   = lane >> 4;

  const int bid = blockIdx.x;
  const int xcd = bid & 7;
  const int s   = bid >> 3;
  const int b   = xcd * 16 + (s >> 3);
  const int c0  = (s & 7) * NC;

  const float* Cb = covTE + (size_t)b * NV * NV;
  const float* Lb = chol  + (size_t)b * NV * NV;
  float*       Ob = out   + (size_t)b * NV * NV;

  {
    const int rr = tid >> 4;
    const int cc = (tid & 15) * 4;
    #pragma unroll
    for (int p = 0; p < 8; ++p) {
      const int r = p * 64 + rr;
      fv4 v = *(const fv4*)(Lb + (size_t)r * NV + c0 + cc);
      *(unsigned short*)(sB0 + swzL(cc + 0, r)) = f2bf(v[0]);
      *(unsigned short*)(sB0 + swzL(cc + 1, r)) = f2bf(v[1]);
      *(unsigned short*)(sB0 + swzL(cc + 2, r)) = f2bf(v[2]);
      *(unsigned short*)(sB0 + swzL(cc + 3, r)) = f2bf(v[3]);
    }
  }
  __syncthreads();

  f32x4 acc[2][4];
  #pragma unroll
  for (int m = 0; m < 2; ++m)
    #pragma unroll
    for (int n = 0; n < 4; ++n) acc[m][n] = (f32x4)0.f;

  for (int kb = 0; kb < 16; ++kb) {
    const int kbase = kb * 32 + lq * 8;
    bf8 bfr[4];
    #pragma unroll
    for (int n = 0; n < 4; ++n)
      bfr[n] = *(const bf8*)(sB0 + swzL(n * 16 + lr, kbase));
    #pragma unroll
    for (int m = 0; m < 2; ++m) {
      const float* p = Cb + (size_t)(w * 32 + m * 16 + lr) * NV + kbase;
      fv4 a0 = *(const fv4*)p;
      fv4 a1 = *(const fv4*)(p + 4);
      u16x8 t;
      t[0]=f2bf(a0[0]); t[1]=f2bf(a0[1]); t[2]=f2bf(a0[2]); t[3]=f2bf(a0[3]);
      t[4]=f2bf(a1[0]); t[5]=f2bf(a1[1]); t[6]=f2bf(a1[2]); t[7]=f2bf(a1[3]);
      bf8 af = __builtin_bit_cast(bf8, t);
      #pragma unroll
      for (int n = 0; n < 4; ++n)
        acc[m][n] = __builtin_amdgcn_mfma_f32_16x16x32_bf16(af, bfr[n], acc[m][n], 0, 0, 0);
    }
  }
  #pragma unroll
  for (int m = 0; m < 2; ++m) {
    #pragma unroll
    for (int n = 0; n < 4; ++n) {
      f32x4 a = acc[m][n];
      u16x4 pk;
      pk[0]=f2bf(a[0]); pk[1]=f2bf(a[1]); pk[2]=f2bf(a[2]); pk[3]=f2bf(a[3]);
      *(u16x4*)(sB1 + swzL(n * 16 + lr, w * 32 + m * 16 + lq * 4)) = pk;
    }
  }
  __syncthreads();

  #pragma unroll
  for (int m = 0; m < 2; ++m)
    #pragma unroll
    for (int n = 0; n < 4; ++n) acc[m][n] = (f32x4)0.f;

  const int sj = (tid & 255) * 2;
  const int so = tid >> 8;

  fv2 raw[8];
  {
    const float* src = Lb + (size_t)(so * 8) * NV + sj;
    #pragma unroll
    for (int r = 0; r < 8; ++r) raw[r] = *(const fv2*)(src + (size_t)r * NV);
    u16x8 p0, p1;
    #pragma unroll
    for (int r = 0; r < 8; ++r) { p0[r] = f2bf(raw[r][0]); p1[r] = f2bf(raw[r][1]); }
    *(u16x8*)(sCh + swzC(sj + 0, so * 8)) = p0;
    *(u16x8*)(sCh + swzC(sj + 1, so * 8)) = p1;
  }
  __syncthreads();

  for (int ib = 0; ib < 16; ++ib) {
    if (ib + 1 < 16) {
      const float* src = Lb + (size_t)((ib + 1) * 32 + so * 8) * NV + sj;
      #pragma unroll
      for (int r = 0; r < 8; ++r) raw[r] = *(const fv2*)(src + (size_t)r * NV);
    }
    bf8 bt[4];
    #pragma unroll
    for (int n = 0; n < 4; ++n)
      bt[n] = *(const bf8*)(sB1 + swzL(n * 16 + lr, ib * 32 + lq * 8));
    #pragma unroll
    for (int jt = 0; jt < 2; ++jt) {
      bf8 af = *(const bf8*)(sCh + swzC(w * 32 + jt * 16 + lr, lq * 8));
      #pragma unroll
      for (int n = 0; n < 4; ++n)
        acc[jt][n] = __builtin_amdgcn_mfma_f32_16x16x32_bf16(af, bt[n], acc[jt][n], 0, 0, 0);
    }
    __syncthreads();
    if (ib + 1 < 16) {
      u16x8 p0, p1;
      #pragma unroll
      for (int r = 0; r < 8; ++r) { p0[r] = f2bf(raw[r][0]); p1[r] = f2bf(raw[r][1]); }
      *(u16x8*)(sCh + swzC(sj + 0, so * 8)) = p0;
      *(u16x8*)(sCh + swzC(sj + 1, so * 8)) = p1;
    }
    __syncthreads();
  }

  #pragma unroll
  for (int jt = 0; jt < 2; ++jt) {
    #pragma unroll
    for (int n = 0; n < 4; ++n) {
      f32x4 a = acc[jt][n];
      const int gk = c0 + n * 16 + lr;
      const int j0 = w * 32 + jt * 16 + lq * 4;
      u16x4 pk;
      #pragma unroll
      for (int q = 0; q < 4; ++q) {
        const int j = j0 + q;
        float f = (j > gk) ? a[q] : ((j == gk) ? 0.5f * a[q] : 0.f);
        pk[q] = f2bf(f);
      }
      *(u16x4*)(sB0 + swzL(n * 16 + lr, j0)) = pk;
    }
  }
  __syncthreads();

  #pragma unroll
  for (int m = 0; m < 2; ++m)
    #pragma unroll
    for (int n = 0; n < 4; ++n) acc[m][n] = (f32x4)0.f;

  for (int kb = 0; kb < 16; ++kb) {
    const int kbase = kb * 32 + lq * 8;
    bf8 bp[4];
    #pragma unroll
    for (int n = 0; n < 4; ++n)
      bp[n] = *(const bf8*)(sB0 + swzL(n * 16 + lr, kbase));
    #pragma unroll
    for (int m = 0; m < 2; ++m) {
      const float* p = Lb + (size_t)(w * 32 + m * 16 + lr) * NV + kbase;
      fv4 a0 = *(const fv4*)p;
      fv4 a1 = *(const fv4*)(p + 4);
      u16x8 t;
      t[0]=f2bf(a0[0]); t[1]=f2bf(a0[1]); t[2]=f2bf(a0[2]); t[3]=f2bf(a0[3]);
      t[4]=f2bf(a1[0]); t[5]=f2bf(a1[1]); t[6]=f2bf(a1[2]); t[7]=f2bf(a1[3]);
      bf8 af = __builtin_bit_cast(bf8, t);
      #pragma unroll
      for (int n = 0; n < 4; ++n)
        acc[m][n] = __builtin_amdgcn_mfma_f32_16x16x32_bf16(af, bp[n], acc[m][n], 0, 0, 0);
    }
  }
  #pragma unroll
  for (int m = 0; m < 2; ++m) {
    const int i0 = w * 32 + m * 16 + lq * 4;
    #pragma unroll
    for (int n = 0; n < 4; ++n) {
      f32x4 a = acc[m][n];
      const int col = c0 + n * 16 + lr;
      #pragma unroll
      for (int q = 0; q < 4; ++q)
        Ob[(size_t)(i0 + q) * NV + col] = -a[q];
    }
  }
}

extern "C" void kernel_launch(void* const* d_in, const int* in_sizes, int n_in,
                              void* d_out, int out_size, void* d_ws, size_t ws_size,
                              hipStream_t stream) {
  const float* muTE  = (const float*)d_in[0];
  const float* covTE = (const float*)d_in[1];
  const float* chol  = (const float*)d_in[2];
  float* out = (float*)d_out;

  // Output 0: muTE passthrough
  hipMemcpyAsync(out, muTE, (size_t)NB * NV * sizeof(float),
                 hipMemcpyDeviceToDevice, stream);

  float* cholTE = out + (size_t)NB * NV;
  const size_t lt_bytes = (size_t)NB * NV * NV * sizeof(unsigned short); // 64 MB

  if (ws_size >= lt_bytes) {
    unsigned short* LT = (unsigned short*)d_ws;
    convert_LT_kernel<<<dim3(NB * 64), dim3(256), 0, stream>>>(chol, LT);
    fused_cholTE_fast<<<dim3(NB * (NV / NC)), dim3(1024), 0, stream>>>(
        covTE, chol, LT, cholTE);
  } else {
    fused_cholTE_fallback<<<dim3(NB * (NV / NC)), dim3(1024), 0, stream>>>(
        covTE, chol, cholTE);
  }
}